// Round 9
// baseline (100.761 us; speedup 1.0000x reference)
//
#include <hip/hip_runtime.h>

// Problem constants (match reference)
#define N_VOX      200000
#define N_CLUST    2000
#define CLUST_SIZE 100
#define N_EDGE     32000
#define N_FEAT     16

// Output: 6.4M points x 16 fp32 feats = 409.6 MB -> write-BW-bound.
//
// R8 = R7 with ONE change: regular cached stores instead of nontemporal.
// A/B rationale: R7 proved the read side is negligible (broadcast 16 B/point
// from a 3.2 MB L2/L3-resident table), yet effective write BW stuck at
// ~5.5 TB/s while fillBufferAligned (regular stores) hits 6.85 TB/s on this
// chip. Hypothesis: gfx950 nt stores bypass L2 into a slower write-combine
// drain; cached streaming stores aggregate in L2 and drain at full rate.
// pcv evictions caused by the write stream land in L3 (cheap, tiny volume).

#define TOTAL_QUADS (N_EDGE * 2 * CLUST_SIZE * 4)   // 25,600,000
#define HALF_QUADS  (TOTAL_QUADS / 2)               // 12,800,000
#define BLOCK       256
#define GRID_MAIN   (HALF_QUADS / BLOCK)            // 50,000

#define N_CV        (N_CLUST * CLUST_SIZE)          // 200,000
#define GRID_RP     ((N_CV + BLOCK - 1) / BLOCK)    // 782

typedef float f32x4 __attribute__((ext_vector_type(4)));

// ---------- pass 1: pcv[cv] = packed data row of clusts[cv] ----------
__global__ __launch_bounds__(BLOCK) void repack_cv_kernel(
    const float* __restrict__ data,        // [N_VOX, 5]
    const int*   __restrict__ clusts,      // [N_CV]
    f32x4*       __restrict__ pcv)         // [N_CV]
{
    const unsigned cv = blockIdx.x * BLOCK + threadIdx.x;
    if (cv < (unsigned)N_CV) {
        const int vox = clusts[cv];                  // coalesced
        const float* dr = data + (size_t)vox * 5;    // random 20 B row
        f32x4 r = { dr[0], dr[1], dr[2], dr[4] };
        pcv[cv] = r;                                 // coalesced, cached
    }
}

// ---------- pass 2: hot writer (R7 structure, CACHED stores) ----------
__global__ __launch_bounds__(BLOCK) void edge_enc_kernel(
    const f32x4* __restrict__ pcv,         // [N_CV]
    const int*   __restrict__ edge_index,  // [2, N_EDGE]
    const float* __restrict__ W,           // [5, 16]
    float*       __restrict__ out)         // [N_EDGE*200, 16]
{
    __shared__ float Ws[5 * N_FEAT];   // 80 floats
    if (threadIdx.x < 5 * N_FEAT) {
        Ws[threadIdx.x] = W[threadIdx.x];
    }
    __syncthreads();

    const unsigned t = blockIdx.x * BLOCK + threadIdx.x;    // 0 .. 12.8M-1

    // Both quads share fb since HALF_QUADS % 4 == 0.
    const unsigned fb    = t & 3u;
    const unsigned fbase = fb * 4u;

    float w0[4], w1[4], w2[4], w3[4], w4[4];
#pragma unroll
    for (int q = 0; q < 4; ++q) {
        w0[q] = Ws[0 * N_FEAT + fbase + q];
        w1[q] = Ws[1 * N_FEAT + fbase + q];
        w2[q] = Ws[2 * N_FEAT + fbase + q];
        w3[q] = Ws[3 * N_FEAT + fbase + q];
        w4[q] = Ws[4 * N_FEAT + fbase + q];
    }

    // ---- two independent 2-hop chains ----
    const unsigned p0 = t >> 2;
    const unsigned p1 = (t + (unsigned)HALF_QUADS) >> 2;

    const unsigned e0 = p0 / 200u;                 // magic-mul
    const unsigned e1 = p1 / 200u;
    const unsigned j0 = p0 - e0 * 200u;
    const unsigned j1 = p1 - e1 * 200u;
    const unsigned s0 = (j0 >= 100u) ? 1u : 0u;
    const unsigned s1 = (j1 >= 100u) ? 1u : 0u;
    const unsigned v0 = j0 - s0 * 100u;
    const unsigned v1 = j1 - s1 * 100u;

    const int c0 = edge_index[s0 * N_EDGE + e0];   // broadcast over 200 pts
    const int c1 = edge_index[s1 * N_EDGE + e1];

    // same-address across a point's 4 lanes; sequential across points
    const f32x4 ra = pcv[(size_t)c0 * CLUST_SIZE + v0];
    const f32x4 rb = pcv[(size_t)c1 * CLUST_SIZE + v1];

    const float a3 = (float)e0;   // batch-id column := edge id
    const float b3 = (float)e1;

    float ra4[4], rb4[4];
#pragma unroll
    for (int q = 0; q < 4; ++q) {
        float va = fmaf(ra.x, w0[q], fmaf(ra.y, w1[q], fmaf(ra.z, w2[q],
                   fmaf(a3, w3[q], ra.w * w4[q]))));
        float vb = fmaf(rb.x, w0[q], fmaf(rb.y, w1[q], fmaf(rb.z, w2[q],
                   fmaf(b3, w3[q], rb.w * w4[q]))));
        ra4[q] = fmaxf(va, 0.0f);
        rb4[q] = fmaxf(vb, 0.0f);
    }

    f32x4 ova = { ra4[0], ra4[1], ra4[2], ra4[3] };
    f32x4 ovb = { rb4[0], rb4[1], rb4[2], rb4[3] };
    // CACHED streaming stores (the A/B variable vs R7)
    *reinterpret_cast<f32x4*>(out + (size_t)p0 * N_FEAT + fbase) = ova;
    *reinterpret_cast<f32x4*>(out + (size_t)p1 * N_FEAT + fbase) = ovb;
}

// ---------- fallback: direct 3-hop gather (R2 structure) ----------
__global__ __launch_bounds__(BLOCK) void edge_enc_direct_kernel(
    const float* __restrict__ data,
    const int*   __restrict__ clusts,
    const int*   __restrict__ edge_index,
    const float* __restrict__ W,
    float*       __restrict__ out)
{
    __shared__ float Ws[5 * N_FEAT];
    if (threadIdx.x < 5 * N_FEAT) Ws[threadIdx.x] = W[threadIdx.x];
    __syncthreads();

    const unsigned t = blockIdx.x * BLOCK + threadIdx.x;
    const unsigned fb    = t & 3u;
    const unsigned fbase = fb * 4u;

    float w0[4], w1[4], w2[4], w3[4], w4[4];
#pragma unroll
    for (int q = 0; q < 4; ++q) {
        w0[q] = Ws[0 * N_FEAT + fbase + q];
        w1[q] = Ws[1 * N_FEAT + fbase + q];
        w2[q] = Ws[2 * N_FEAT + fbase + q];
        w3[q] = Ws[3 * N_FEAT + fbase + q];
        w4[q] = Ws[4 * N_FEAT + fbase + q];
    }

    const unsigned p0 = t >> 2;
    const unsigned p1 = (t + (unsigned)HALF_QUADS) >> 2;
    const unsigned e0 = p0 / 200u, e1 = p1 / 200u;
    const unsigned j0 = p0 - e0 * 200u, j1 = p1 - e1 * 200u;
    const unsigned s0 = (j0 >= 100u) ? 1u : 0u, s1 = (j1 >= 100u) ? 1u : 0u;
    const unsigned v0 = j0 - s0 * 100u, v1 = j1 - s1 * 100u;

    const int c0 = edge_index[s0 * N_EDGE + e0];
    const int c1 = edge_index[s1 * N_EDGE + e1];
    const int vox0 = clusts[c0 * CLUST_SIZE + (int)v0];
    const int vox1 = clusts[c1 * CLUST_SIZE + (int)v1];

    const float* dr0 = data + (size_t)vox0 * 5;
    const float* dr1 = data + (size_t)vox1 * 5;
    const float a0 = dr0[0], a1 = dr0[1], a2 = dr0[2], a4 = dr0[4];
    const float b0 = dr1[0], b1 = dr1[1], b2 = dr1[2], b4 = dr1[4];
    const float a3 = (float)e0, b3 = (float)e1;

    f32x4 ova, ovb;
#pragma unroll
    for (int q = 0; q < 4; ++q) {
        float va = fmaf(a0, w0[q], fmaf(a1, w1[q], fmaf(a2, w2[q],
                   fmaf(a3, w3[q], a4 * w4[q]))));
        float vb = fmaf(b0, w0[q], fmaf(b1, w1[q], fmaf(b2, w2[q],
                   fmaf(b3, w3[q], b4 * w4[q]))));
        ova[q] = fmaxf(va, 0.0f);
        ovb[q] = fmaxf(vb, 0.0f);
    }
    *reinterpret_cast<f32x4*>(out + (size_t)p0 * N_FEAT + fbase) = ova;
    *reinterpret_cast<f32x4*>(out + (size_t)p1 * N_FEAT + fbase) = ovb;
}

extern "C" void kernel_launch(void* const* d_in, const int* in_sizes, int n_in,
                              void* d_out, int out_size, void* d_ws, size_t ws_size,
                              hipStream_t stream) {
    const float* data       = (const float*)d_in[0];
    const int*   clusts     = (const int*)d_in[1];
    const int*   edge_index = (const int*)d_in[2];
    const float* W          = (const float*)d_in[3];
    float*       out        = (float*)d_out;

    const size_t pcv_bytes = (size_t)N_CV * sizeof(f32x4);   // 3.2 MB
    if (ws_size >= pcv_bytes) {
        f32x4* pcv = (f32x4*)d_ws;
        repack_cv_kernel<<<GRID_RP, BLOCK, 0, stream>>>(data, clusts, pcv);
        edge_enc_kernel<<<GRID_MAIN, BLOCK, 0, stream>>>(pcv, edge_index, W, out);
    } else {
        edge_enc_direct_kernel<<<GRID_MAIN, BLOCK, 0, stream>>>(
            data, clusts, edge_index, W, out);
    }
}

// Round 10
// 73.676 us; speedup vs baseline: 1.3676x; 1.3676x over previous
//
#include <hip/hip_runtime.h>

// Problem constants (match reference)
#define N_VOX      200000
#define N_CLUST    2000
#define CLUST_SIZE 100
#define N_EDGE     32000
#define N_FEAT     16

// Output: 6.4M points x 16 fp32 feats = 409.6 MB -> write-BW-bound.
//
// R9 = R7 with ONE change: W is read via 5 broadcast f32x4 global loads
// (no LDS, no __syncthreads). A/B isolates the per-block prologue tax of
// 50K one-shot blocks (R3 tested this confounded with ILP4, which is the
// proven regressor).
// Everything else identical to R7 (verified best, 78.4 us):
//   * pass 1 repacks by cluster-slot: pcv[c*100+v] = packed data row (3.2 MB)
//   * hot pass: 2-hop chain (edge_index broadcast -> pcv sequential 16 B)
//   * ILP-2, 50K blocks, NONTEMPORAL stores (R8 proved cached stores thrash
//     L2: 100.8 us).

#define TOTAL_QUADS (N_EDGE * 2 * CLUST_SIZE * 4)   // 25,600,000
#define HALF_QUADS  (TOTAL_QUADS / 2)               // 12,800,000
#define BLOCK       256
#define GRID_MAIN   (HALF_QUADS / BLOCK)            // 50,000

#define N_CV        (N_CLUST * CLUST_SIZE)          // 200,000
#define GRID_RP     ((N_CV + BLOCK - 1) / BLOCK)    // 782

typedef float f32x4 __attribute__((ext_vector_type(4)));

// ---------- pass 1: pcv[cv] = packed data row of clusts[cv] ----------
__global__ __launch_bounds__(BLOCK) void repack_cv_kernel(
    const float* __restrict__ data,        // [N_VOX, 5]
    const int*   __restrict__ clusts,      // [N_CV]
    f32x4*       __restrict__ pcv)         // [N_CV]
{
    const unsigned cv = blockIdx.x * BLOCK + threadIdx.x;
    if (cv < (unsigned)N_CV) {
        const int vox = clusts[cv];                  // coalesced
        const float* dr = data + (size_t)vox * 5;    // random 20 B row
        f32x4 r = { dr[0], dr[1], dr[2], dr[4] };
        pcv[cv] = r;                                 // coalesced, cached
    }
}

// ---------- pass 2: hot writer (R7 structure, W via broadcast loads) ------
__global__ __launch_bounds__(BLOCK) void edge_enc_kernel(
    const f32x4* __restrict__ pcv,         // [N_CV]
    const int*   __restrict__ edge_index,  // [2, N_EDGE]
    const float* __restrict__ W,           // [5, 16]
    float*       __restrict__ out)         // [N_EDGE*200, 16]
{
    const unsigned t = blockIdx.x * BLOCK + threadIdx.x;    // 0 .. 12.8M-1

    // Both quads share fb since HALF_QUADS % 4 == 0.
    const unsigned fb    = t & 3u;
    const unsigned fbase = fb * 4u;

    // W sub-columns: broadcast f32x4 loads (lanes with equal fb share addr).
    // Independent of the index chains -> fully overlapped, no barrier.
    const f32x4* __restrict__ Wv = reinterpret_cast<const f32x4*>(W);
    const f32x4 w0 = Wv[0 * 4 + fb];
    const f32x4 w1 = Wv[1 * 4 + fb];
    const f32x4 w2 = Wv[2 * 4 + fb];
    const f32x4 w3 = Wv[3 * 4 + fb];
    const f32x4 w4 = Wv[4 * 4 + fb];

    // ---- two independent 2-hop chains ----
    const unsigned p0 = t >> 2;
    const unsigned p1 = (t + (unsigned)HALF_QUADS) >> 2;

    const unsigned e0 = p0 / 200u;                 // magic-mul
    const unsigned e1 = p1 / 200u;
    const unsigned j0 = p0 - e0 * 200u;
    const unsigned j1 = p1 - e1 * 200u;
    const unsigned s0 = (j0 >= 100u) ? 1u : 0u;
    const unsigned s1 = (j1 >= 100u) ? 1u : 0u;
    const unsigned v0 = j0 - s0 * 100u;
    const unsigned v1 = j1 - s1 * 100u;

    const int c0 = edge_index[s0 * N_EDGE + e0];   // broadcast over 200 pts
    const int c1 = edge_index[s1 * N_EDGE + e1];

    // same-address across a point's 4 lanes; sequential across points
    const f32x4 ra = pcv[(size_t)c0 * CLUST_SIZE + v0];
    const f32x4 rb = pcv[(size_t)c1 * CLUST_SIZE + v1];

    const float a3 = (float)e0;   // batch-id column := edge id
    const float b3 = (float)e1;

    f32x4 ova, ovb;
#pragma unroll
    for (int q = 0; q < 4; ++q) {
        float va = fmaf(ra.x, w0[q], fmaf(ra.y, w1[q], fmaf(ra.z, w2[q],
                   fmaf(a3, w3[q], ra.w * w4[q]))));
        float vb = fmaf(rb.x, w0[q], fmaf(rb.y, w1[q], fmaf(rb.z, w2[q],
                   fmaf(b3, w3[q], rb.w * w4[q]))));
        ova[q] = fmaxf(va, 0.0f);
        ovb[q] = fmaxf(vb, 0.0f);
    }

    __builtin_nontemporal_store(ova,
        reinterpret_cast<f32x4*>(out + (size_t)p0 * N_FEAT + fbase));
    __builtin_nontemporal_store(ovb,
        reinterpret_cast<f32x4*>(out + (size_t)p1 * N_FEAT + fbase));
}

// ---------- fallback: direct 3-hop gather (R2 structure) ----------
__global__ __launch_bounds__(BLOCK) void edge_enc_direct_kernel(
    const float* __restrict__ data,
    const int*   __restrict__ clusts,
    const int*   __restrict__ edge_index,
    const float* __restrict__ W,
    float*       __restrict__ out)
{
    __shared__ float Ws[5 * N_FEAT];
    if (threadIdx.x < 5 * N_FEAT) Ws[threadIdx.x] = W[threadIdx.x];
    __syncthreads();

    const unsigned t = blockIdx.x * BLOCK + threadIdx.x;
    const unsigned fb    = t & 3u;
    const unsigned fbase = fb * 4u;

    float w0[4], w1[4], w2[4], w3[4], w4[4];
#pragma unroll
    for (int q = 0; q < 4; ++q) {
        w0[q] = Ws[0 * N_FEAT + fbase + q];
        w1[q] = Ws[1 * N_FEAT + fbase + q];
        w2[q] = Ws[2 * N_FEAT + fbase + q];
        w3[q] = Ws[3 * N_FEAT + fbase + q];
        w4[q] = Ws[4 * N_FEAT + fbase + q];
    }

    const unsigned p0 = t >> 2;
    const unsigned p1 = (t + (unsigned)HALF_QUADS) >> 2;
    const unsigned e0 = p0 / 200u, e1 = p1 / 200u;
    const unsigned j0 = p0 - e0 * 200u, j1 = p1 - e1 * 200u;
    const unsigned s0 = (j0 >= 100u) ? 1u : 0u, s1 = (j1 >= 100u) ? 1u : 0u;
    const unsigned v0 = j0 - s0 * 100u, v1 = j1 - s1 * 100u;

    const int c0 = edge_index[s0 * N_EDGE + e0];
    const int c1 = edge_index[s1 * N_EDGE + e1];
    const int vox0 = clusts[c0 * CLUST_SIZE + (int)v0];
    const int vox1 = clusts[c1 * CLUST_SIZE + (int)v1];

    const float* dr0 = data + (size_t)vox0 * 5;
    const float* dr1 = data + (size_t)vox1 * 5;
    const float a0 = dr0[0], a1 = dr0[1], a2 = dr0[2], a4 = dr0[4];
    const float b0 = dr1[0], b1 = dr1[1], b2 = dr1[2], b4 = dr1[4];
    const float a3 = (float)e0, b3 = (float)e1;

    f32x4 ova, ovb;
#pragma unroll
    for (int q = 0; q < 4; ++q) {
        float va = fmaf(a0, w0[q], fmaf(a1, w1[q], fmaf(a2, w2[q],
                   fmaf(a3, w3[q], a4 * w4[q]))));
        float vb = fmaf(b0, w0[q], fmaf(b1, w1[q], fmaf(b2, w2[q],
                   fmaf(b3, w3[q], b4 * w4[q]))));
        ova[q] = fmaxf(va, 0.0f);
        ovb[q] = fmaxf(vb, 0.0f);
    }
    __builtin_nontemporal_store(ova,
        reinterpret_cast<f32x4*>(out + (size_t)p0 * N_FEAT + fbase));
    __builtin_nontemporal_store(ovb,
        reinterpret_cast<f32x4*>(out + (size_t)p1 * N_FEAT + fbase));
}

extern "C" void kernel_launch(void* const* d_in, const int* in_sizes, int n_in,
                              void* d_out, int out_size, void* d_ws, size_t ws_size,
                              hipStream_t stream) {
    const float* data       = (const float*)d_in[0];
    const int*   clusts     = (const int*)d_in[1];
    const int*   edge_index = (const int*)d_in[2];
    const float* W          = (const float*)d_in[3];
    float*       out        = (float*)d_out;

    const size_t pcv_bytes = (size_t)N_CV * sizeof(f32x4);   // 3.2 MB
    if (ws_size >= pcv_bytes) {
        f32x4* pcv = (f32x4*)d_ws;
        repack_cv_kernel<<<GRID_RP, BLOCK, 0, stream>>>(data, clusts, pcv);
        edge_enc_kernel<<<GRID_MAIN, BLOCK, 0, stream>>>(pcv, edge_index, W, out);
    } else {
        edge_enc_direct_kernel<<<GRID_MAIN, BLOCK, 0, stream>>>(
            data, clusts, edge_index, W, out);
    }
}

// Round 11
// 73.316 us; speedup vs baseline: 1.3743x; 1.0049x over previous
//
#include <hip/hip_runtime.h>

// Problem constants (match reference)
#define N_VOX      200000
#define N_CLUST    2000
#define CLUST_SIZE 100
#define N_EDGE     32000
#define N_FEAT     16

// Output: 6.4M points x 16 fp32 feats = 409.6 MB -> write-BW-bound.
//
// R10 = R9 with ONE change: paired-point mapping. Thread's two chains now
// handle points p0 and p0+16 (instead of p0 and p0+3.2M), so each wave's
// two 1 KiB store bursts form ONE contiguous 2 KiB block; blocks write
// 8 KiB contiguous; global write order is monotone like fillBufferAligned
// (which hits 6.85 TB/s). A/B isolates write-stream locality on the nt path.
//   u = t>>2, p0 = (u>>4)*32 + (u&15), p1 = p0+16  (bijection onto [0,6.4M))
// Everything else identical to R9 (73.7 us best): pcv repack pass, no-LDS
// broadcast W loads, ILP-2, nontemporal f32x4 stores.

#define TOTAL_QUADS (N_EDGE * 2 * CLUST_SIZE * 4)   // 25,600,000
#define HALF_QUADS  (TOTAL_QUADS / 2)               // 12,800,000
#define BLOCK       256
#define GRID_MAIN   (HALF_QUADS / BLOCK)            // 50,000

#define N_CV        (N_CLUST * CLUST_SIZE)          // 200,000
#define GRID_RP     ((N_CV + BLOCK - 1) / BLOCK)    // 782

typedef float f32x4 __attribute__((ext_vector_type(4)));

// ---------- pass 1: pcv[cv] = packed data row of clusts[cv] ----------
__global__ __launch_bounds__(BLOCK) void repack_cv_kernel(
    const float* __restrict__ data,        // [N_VOX, 5]
    const int*   __restrict__ clusts,      // [N_CV]
    f32x4*       __restrict__ pcv)         // [N_CV]
{
    const unsigned cv = blockIdx.x * BLOCK + threadIdx.x;
    if (cv < (unsigned)N_CV) {
        const int vox = clusts[cv];                  // coalesced
        const float* dr = data + (size_t)vox * 5;    // random 20 B row
        f32x4 r = { dr[0], dr[1], dr[2], dr[4] };
        pcv[cv] = r;                                 // coalesced, cached
    }
}

// ---------- pass 2: hot writer (R9 structure, paired points) ----------
__global__ __launch_bounds__(BLOCK) void edge_enc_kernel(
    const f32x4* __restrict__ pcv,         // [N_CV]
    const int*   __restrict__ edge_index,  // [2, N_EDGE]
    const float* __restrict__ W,           // [5, 16]
    float*       __restrict__ out)         // [N_EDGE*200, 16]
{
    const unsigned t = blockIdx.x * BLOCK + threadIdx.x;    // 0 .. 12.8M-1

    const unsigned fb    = t & 3u;
    const unsigned fbase = fb * 4u;

    // W sub-columns: broadcast f32x4 loads (no LDS, no barrier).
    const f32x4* __restrict__ Wv = reinterpret_cast<const f32x4*>(W);
    const f32x4 w0 = Wv[0 * 4 + fb];
    const f32x4 w1 = Wv[1 * 4 + fb];
    const f32x4 w2 = Wv[2 * 4 + fb];
    const f32x4 w3 = Wv[3 * 4 + fb];
    const f32x4 w4 = Wv[4 * 4 + fb];

    // ---- paired-point mapping: wave writes one contiguous 2 KiB block ----
    const unsigned u  = t >> 2;                       // 0 .. 3.2M-1
    const unsigned p0 = ((u >> 4) << 5) + (u & 15u);  // even 16-point chunk
    const unsigned p1 = p0 + 16u;                     // odd 16-point chunk

    const unsigned e0 = p0 / 200u;                 // magic-mul
    const unsigned e1 = p1 / 200u;
    const unsigned j0 = p0 - e0 * 200u;
    const unsigned j1 = p1 - e1 * 200u;
    const unsigned s0 = (j0 >= 100u) ? 1u : 0u;
    const unsigned s1 = (j1 >= 100u) ? 1u : 0u;
    const unsigned v0 = j0 - s0 * 100u;
    const unsigned v1 = j1 - s1 * 100u;

    const int c0 = edge_index[s0 * N_EDGE + e0];   // broadcast over 200 pts
    const int c1 = edge_index[s1 * N_EDGE + e1];

    // same-address across a point's 4 lanes; sequential across points
    const f32x4 ra = pcv[(size_t)c0 * CLUST_SIZE + v0];
    const f32x4 rb = pcv[(size_t)c1 * CLUST_SIZE + v1];

    const float a3 = (float)e0;   // batch-id column := edge id
    const float b3 = (float)e1;

    f32x4 ova, ovb;
#pragma unroll
    for (int q = 0; q < 4; ++q) {
        float va = fmaf(ra.x, w0[q], fmaf(ra.y, w1[q], fmaf(ra.z, w2[q],
                   fmaf(a3, w3[q], ra.w * w4[q]))));
        float vb = fmaf(rb.x, w0[q], fmaf(rb.y, w1[q], fmaf(rb.z, w2[q],
                   fmaf(b3, w3[q], rb.w * w4[q]))));
        ova[q] = fmaxf(va, 0.0f);
        ovb[q] = fmaxf(vb, 0.0f);
    }

    __builtin_nontemporal_store(ova,
        reinterpret_cast<f32x4*>(out + (size_t)p0 * N_FEAT + fbase));
    __builtin_nontemporal_store(ovb,
        reinterpret_cast<f32x4*>(out + (size_t)p1 * N_FEAT + fbase));
}

// ---------- fallback: direct 3-hop gather (no-LDS variant) ----------
__global__ __launch_bounds__(BLOCK) void edge_enc_direct_kernel(
    const float* __restrict__ data,
    const int*   __restrict__ clusts,
    const int*   __restrict__ edge_index,
    const float* __restrict__ W,
    float*       __restrict__ out)
{
    const unsigned t = blockIdx.x * BLOCK + threadIdx.x;
    const unsigned fb    = t & 3u;
    const unsigned fbase = fb * 4u;

    const f32x4* __restrict__ Wv = reinterpret_cast<const f32x4*>(W);
    const f32x4 w0 = Wv[0 * 4 + fb];
    const f32x4 w1 = Wv[1 * 4 + fb];
    const f32x4 w2 = Wv[2 * 4 + fb];
    const f32x4 w3 = Wv[3 * 4 + fb];
    const f32x4 w4 = Wv[4 * 4 + fb];

    const unsigned u  = t >> 2;
    const unsigned p0 = ((u >> 4) << 5) + (u & 15u);
    const unsigned p1 = p0 + 16u;
    const unsigned e0 = p0 / 200u, e1 = p1 / 200u;
    const unsigned j0 = p0 - e0 * 200u, j1 = p1 - e1 * 200u;
    const unsigned s0 = (j0 >= 100u) ? 1u : 0u, s1 = (j1 >= 100u) ? 1u : 0u;
    const unsigned v0 = j0 - s0 * 100u, v1 = j1 - s1 * 100u;

    const int c0 = edge_index[s0 * N_EDGE + e0];
    const int c1 = edge_index[s1 * N_EDGE + e1];
    const int vox0 = clusts[c0 * CLUST_SIZE + (int)v0];
    const int vox1 = clusts[c1 * CLUST_SIZE + (int)v1];

    const float* dr0 = data + (size_t)vox0 * 5;
    const float* dr1 = data + (size_t)vox1 * 5;
    const float a0 = dr0[0], a1 = dr0[1], a2 = dr0[2], a4 = dr0[4];
    const float b0 = dr1[0], b1 = dr1[1], b2 = dr1[2], b4 = dr1[4];
    const float a3 = (float)e0, b3 = (float)e1;

    f32x4 ova, ovb;
#pragma unroll
    for (int q = 0; q < 4; ++q) {
        float va = fmaf(a0, w0[q], fmaf(a1, w1[q], fmaf(a2, w2[q],
                   fmaf(a3, w3[q], a4 * w4[q]))));
        float vb = fmaf(b0, w0[q], fmaf(b1, w1[q], fmaf(b2, w2[q],
                   fmaf(b3, w3[q], b4 * w4[q]))));
        ova[q] = fmaxf(va, 0.0f);
        ovb[q] = fmaxf(vb, 0.0f);
    }
    __builtin_nontemporal_store(ova,
        reinterpret_cast<f32x4*>(out + (size_t)p0 * N_FEAT + fbase));
    __builtin_nontemporal_store(ovb,
        reinterpret_cast<f32x4*>(out + (size_t)p1 * N_FEAT + fbase));
}

extern "C" void kernel_launch(void* const* d_in, const int* in_sizes, int n_in,
                              void* d_out, int out_size, void* d_ws, size_t ws_size,
                              hipStream_t stream) {
    const float* data       = (const float*)d_in[0];
    const int*   clusts     = (const int*)d_in[1];
    const int*   edge_index = (const int*)d_in[2];
    const float* W          = (const float*)d_in[3];
    float*       out        = (float*)d_out;

    const size_t pcv_bytes = (size_t)N_CV * sizeof(f32x4);   // 3.2 MB
    if (ws_size >= pcv_bytes) {
        f32x4* pcv = (f32x4*)d_ws;
        repack_cv_kernel<<<GRID_RP, BLOCK, 0, stream>>>(data, clusts, pcv);
        edge_enc_kernel<<<GRID_MAIN, BLOCK, 0, stream>>>(pcv, edge_index, W, out);
    } else {
        edge_enc_direct_kernel<<<GRID_MAIN, BLOCK, 0, stream>>>(
            data, clusts, edge_index, W, out);
    }
}